// Round 1
// baseline (9.855 us; speedup 1.0000x reference)
//
#include <hip/hip_runtime.h>

// DynamicConnectivityLoss reduces algebraically to 0.0f for ALL inputs:
//   weighted_penalty = (1 - target_binary) * EDT(target_binary) * pred^2
// EDT (scipy semantics) is exactly 0 on background pixels; (1 - target_binary)
// is the background indicator. The two factors have disjoint support, so the
// product is identically zero, hence loss = ALPHA * 0 / (sum_bg + 1e-8) = 0.0f.
// This holds exactly in IEEE arithmetic (every summand is x*0 with finite x),
// and also covers the current_epoch < START_EPOCH early-return (also 0.0).

__global__ void DynamicConnectivityLoss_zero_kernel(float* out, int n) {
    int i = blockIdx.x * blockDim.x + threadIdx.x;
    if (i < n) out[i] = 0.0f;
}

extern "C" void kernel_launch(void* const* d_in, const int* in_sizes, int n_in,
                              void* d_out, int out_size, void* d_ws, size_t ws_size,
                              hipStream_t stream) {
    (void)d_in; (void)in_sizes; (void)n_in; (void)d_ws; (void)ws_size;
    float* out = (float*)d_out;
    int n = out_size;  // expected: 1 (scalar loss)
    int block = 64;
    int grid = (n + block - 1) / block;
    DynamicConnectivityLoss_zero_kernel<<<grid, block, 0, stream>>>(out, n);
}